// Round 6
// baseline (245.999 us; speedup 1.0000x reference)
//
#include <hip/hip_runtime.h>
#include <math.h>

// GCN 2-layer: out = Anorm( relu( Anorm(X W1) + b1 ) W2 ) + b2
// R6: (a) union kernels INTERLEAVE block types (blockIdx%4) instead of range
//     concat (R5's ranges serialized: all fill blocks dispatched first);
//     (b) gemm1 de-coupled from dinv (h1 stored unscaled; aggemm gathers
//     dinv[src] per edge) -> gemm1 split across dispatch 2 (w/ count) and
//     dispatch 5 (w/ fill), hiding the whole CSR build;
//     (c) gather loops: clamped-index masked unroll-8 (8 rows in flight even
//     at mean degree 6; R5's x4+tail ran depth-1 most of the time).

typedef __bf16 bf16x8 __attribute__((ext_vector_type(8)));
typedef float f32x4 __attribute__((ext_vector_type(4)));

union ABu {
  unsigned short u16[8];
  uint4 u4;
  bf16x8 v;
};

__device__ inline unsigned short f2bf(float f) {  // RNE
  unsigned u = __float_as_uint(f);
  return (unsigned short)((u + 0x7fffu + ((u >> 16) & 1u)) >> 16);
}

__device__ inline void unpack8(uint4 v, float* f) {
  f[0] = __uint_as_float(v.x << 16);
  f[1] = __uint_as_float(v.x & 0xffff0000u);
  f[2] = __uint_as_float(v.y << 16);
  f[3] = __uint_as_float(v.y & 0xffff0000u);
  f[4] = __uint_as_float(v.z << 16);
  f[5] = __uint_as_float(v.z & 0xffff0000u);
  f[6] = __uint_as_float(v.w << 16);
  f[7] = __uint_as_float(v.w & 0xffff0000u);
}

__device__ inline uint4 pack8(const float* a) {
  uint4 o;
  o.x = (unsigned)f2bf(a[0]) | ((unsigned)f2bf(a[1]) << 16);
  o.y = (unsigned)f2bf(a[2]) | ((unsigned)f2bf(a[3]) << 16);
  o.z = (unsigned)f2bf(a[4]) | ((unsigned)f2bf(a[5]) << 16);
  o.w = (unsigned)f2bf(a[6]) | ((unsigned)f2bf(a[7]) << 16);
  return o;
}

constexpr int SCAN_CHUNK = 1024;

// ---------------- shared gemm1 tile body ----------------
// h1[row0..row0+64, 0..128](bf16, UNSCALED) = X[.,128] @ W1
// A-frag: A[m=lane&15][k=(lane>>4)*8+j]; C/D: col=lane&15, row=(lane>>4)*4+reg
__device__ inline void gemm1_tile(const float* __restrict__ X,
                                  const unsigned short* __restrict__ Wb,
                                  unsigned short* __restrict__ Cb, int M,
                                  int row0w, int tid) {
  constexpr int K = 128, N = 128, NT = N / 16, KS = K / 32;
  const int wave = tid >> 6;
  const int lane = tid & 63;
  const int q = lane >> 4;
  const int l15 = lane & 15;
  const int row0 = row0w + wave * 16;
  const int rowA = row0 + l15;

  f32x4 zero = {0.0f, 0.0f, 0.0f, 0.0f};
  f32x4 acc[NT];
#pragma unroll
  for (int t = 0; t < NT; ++t) acc[t] = zero;

#pragma unroll
  for (int kk = 0; kk < KS; ++kk) {
    ABu a;
    float4 f0 = make_float4(0.f, 0.f, 0.f, 0.f);
    float4 f1 = make_float4(0.f, 0.f, 0.f, 0.f);
    if (rowA < M) {
      const float4* ap = (const float4*)(X + (size_t)rowA * K + kk * 32 + q * 8);
      f0 = ap[0];
      f1 = ap[1];
    }
    a.u16[0] = f2bf(f0.x); a.u16[1] = f2bf(f0.y);
    a.u16[2] = f2bf(f0.z); a.u16[3] = f2bf(f0.w);
    a.u16[4] = f2bf(f1.x); a.u16[5] = f2bf(f1.y);
    a.u16[6] = f2bf(f1.z); a.u16[7] = f2bf(f1.w);
#pragma unroll
    for (int nt = 0; nt < NT; ++nt) {
      ABu b;
      b.u4 = *(const uint4*)(Wb + ((size_t)(kk * 4 + q) * N + nt * 16 + l15) * 8);
      acc[nt] = __builtin_amdgcn_mfma_f32_16x16x32_bf16(a.v, b.v, acc[nt], 0, 0, 0);
    }
  }

#pragma unroll
  for (int v = 0; v < 4; ++v) {
    int row = row0 + q * 4 + v;
    if (row < M) {
#pragma unroll
      for (int nt = 0; nt < NT; ++nt)
        Cb[(size_t)row * N + nt * 16 + l15] = f2bf(acc[nt][v]);
    }
  }
}

// ---------------- 1: convW ∪ zero ----------------
// Wb[((k>>3)*N + n)*8 + (k&7)] = bf16(W[k*N+n])
__global__ __launch_bounds__(256) void k_pre(const float* __restrict__ W1,
                                             const float* __restrict__ W2,
                                             unsigned short* __restrict__ Wb1,
                                             unsigned short* __restrict__ Wb2,
                                             int* __restrict__ counts, int n) {
  constexpr int CONV_BLOCKS = (128 * 128 + 128 * 64) / 256;  // 96
  if (blockIdx.x < CONV_BLOCKS) {
    int idx = blockIdx.x * 256 + threadIdx.x;
    if (idx < 128 * 128) {
      int k = idx >> 7, c = idx & 127;
      Wb1[(((k >> 3) << 7) + c) * 8 + (k & 7)] = f2bf(W1[idx]);
    } else {
      int j = idx - 128 * 128;
      int k = j >> 6, c = j & 63;
      Wb2[(((k >> 3) << 6) + c) * 8 + (k & 7)] = f2bf(W2[j]);
    }
    return;
  }
  int i = (blockIdx.x - CONV_BLOCKS) * 256 + threadIdx.x;
  if (i < n) counts[i] = 0;
}

// ---------------- 2: count ∪ gemm1a (interleaved 3:1) ----------------
__global__ __launch_bounds__(256) void k_count_gemm1a(const int* __restrict__ dst,
                                                      int* __restrict__ counts, int E,
                                                      const float* __restrict__ X,
                                                      const unsigned short* __restrict__ Wb,
                                                      unsigned short* __restrict__ Cb,
                                                      int M, int CGRP) {
  const int g = blockIdx.x >> 2;
  const int r = blockIdx.x & 3;
  if (r < 3) {
    int cid = g * 3 + r;
    int e = cid * 256 + threadIdx.x;
    if (e < E) atomicAdd(&counts[dst[e]], 1);
    return;
  }
  // gemm1 rows [0, CGRP*64): one 64-row tile per group
  gemm1_tile(X, Wb, Cb, M, g * 64, threadIdx.x);
}

// ---------------- 3: per-chunk scan ----------------
__global__ __launch_bounds__(256) void k_scan1(const int* __restrict__ counts,
                                               int* __restrict__ offsets,
                                               int* __restrict__ aux, int n) {
  __shared__ int tsum[256];
  int tid = threadIdx.x;
  int base = blockIdx.x * SCAN_CHUNK + tid * 4;
  int v0 = (base + 0 < n) ? counts[base + 0] : 0;
  int v1 = (base + 1 < n) ? counts[base + 1] : 0;
  int v2 = (base + 2 < n) ? counts[base + 2] : 0;
  int v3 = (base + 3 < n) ? counts[base + 3] : 0;
  int s = v0 + v1 + v2 + v3;
  tsum[tid] = s;
  __syncthreads();
  for (int off = 1; off < 256; off <<= 1) {
    int t = (tid >= off) ? tsum[tid - off] : 0;
    __syncthreads();
    tsum[tid] += t;
    __syncthreads();
  }
  int excl = tsum[tid] - s;
  if (base + 0 < n) offsets[base + 0] = excl;
  if (base + 1 < n) offsets[base + 1] = excl + v0;
  if (base + 2 < n) offsets[base + 2] = excl + v0 + v1;
  if (base + 3 < n) offsets[base + 3] = excl + v0 + v1 + v2;
  if (tid == 255) aux[blockIdx.x] = tsum[255];
}

// ---------------- 4: aux-scan (redundant/block) + fixup + dinv ----------------
__global__ __launch_bounds__(256) void k_scan3_dinv(int* __restrict__ offsets,
                                                    const int* __restrict__ aux,
                                                    int* __restrict__ cursor,
                                                    const int* __restrict__ counts,
                                                    float* __restrict__ dinv,
                                                    int n, int E, int G) {
  __shared__ int saux[256];
  int tid = threadIdx.x;
  int v = (tid < G) ? aux[tid] : 0;
  saux[tid] = v;
  __syncthreads();
  for (int off = 1; off < 256; off <<= 1) {
    int t = (tid >= off) ? saux[tid - off] : 0;
    __syncthreads();
    saux[tid] += t;
    __syncthreads();
  }
  int excl = saux[tid] - v;
  __syncthreads();
  saux[tid] = excl;
  __syncthreads();

  int i = blockIdx.x * 256 + tid;
  if (i < n) {
    int o = offsets[i] + saux[i >> 10];
    offsets[i] = o;
    cursor[i] = o;
    dinv[i] = rsqrtf((float)(counts[i] + 1));
  }
  if (i == 0) offsets[n] = E;
}

// ---------------- 5: fill ∪ gemm1b (interleaved 3:1) ----------------
__global__ __launch_bounds__(256) void k_fill_gemm1b(const int* __restrict__ src,
                                                     const int* __restrict__ dst,
                                                     int* __restrict__ cursor,
                                                     int* __restrict__ esrc, int E,
                                                     const float* __restrict__ X,
                                                     const unsigned short* __restrict__ Wb,
                                                     unsigned short* __restrict__ Cb,
                                                     int M, int ROW0) {
  const int g = blockIdx.x >> 2;
  const int r = blockIdx.x & 3;
  if (r < 3) {
    int fid = g * 3 + r;
    int e = fid * 256 + threadIdx.x;
    if (e < E) {
      int s = src[e];
      int d = dst[e];
      int pos = atomicAdd(&cursor[d], 1);
      esrc[pos] = s;
    }
    return;
  }
  gemm1_tile(X, Wb, Cb, M, ROW0 + g * 64, threadIdx.x);
}

// ---------------- 6: fused agg1 + GEMM2 ----------------
// acc_inner = di*h1[node] + sum_e dinv[esrc]*h1[esrc]
// ag = bf16(relu(di*acc_inner + b1)) -> LDS; h2s = (ag @ W2) * di (bf16)
__global__ __launch_bounds__(256) void k_aggemm(const unsigned short* __restrict__ h1s,
                                                const float* __restrict__ dinv,
                                                const float* __restrict__ b1,
                                                const int* __restrict__ offsets,
                                                const int* __restrict__ esrc,
                                                const unsigned short* __restrict__ Wb2,
                                                unsigned short* __restrict__ h2s,
                                                int n) {
  constexpr int LDA = 136;  // 128 + 8 pad, rows 16B-aligned
  __shared__ unsigned short As[16 * LDA];
  __shared__ float sdinv[16];
  const int tid = threadIdx.x;

  // phase 1: 16 nodes, 16 lanes each (8 ch/lane); masked unroll-8 gather
  {
    const int nl = tid >> 4;
    const int q = tid & 15;
    const int node = blockIdx.x * 16 + nl;
    float acc[8];
    if (node < n) {
      const uint4* h4 = (const uint4*)h1s;
      float di = dinv[node];
      if (q == 0) sdinv[nl] = di;
      float hs[8];
      unpack8(h4[(size_t)node * 16 + q], hs);
#pragma unroll
      for (int i = 0; i < 8; ++i) acc[i] = hs[i] * di;  // self (h1 unscaled)
      int e0 = offsets[node];
      int e1 = offsets[node + 1];
      for (int e = e0; e < e1; e += 8) {
        int idx[8];
#pragma unroll
        for (int i = 0; i < 8; ++i) {
          int ee = e + i < e1 ? e + i : e1 - 1;
          idx[i] = esrc[ee];
        }
        uint4 rr[8];
        float dv[8];
#pragma unroll
        for (int i = 0; i < 8; ++i) {
          rr[i] = h4[(size_t)idx[i] * 16 + q];
          dv[i] = dinv[idx[i]];
        }
#pragma unroll
        for (int i = 0; i < 8; ++i) {
          float w = (e + i < e1) ? dv[i] : 0.f;
          float g[8];
          unpack8(rr[i], g);
#pragma unroll
          for (int j = 0; j < 8; ++j) acc[j] = fmaf(g[j], w, acc[j]);
        }
      }
      const float4* b14 = (const float4*)b1;
      float4 ba = b14[q * 2], bb = b14[q * 2 + 1];
      float bias[8] = {ba.x, ba.y, ba.z, ba.w, bb.x, bb.y, bb.z, bb.w};
#pragma unroll
      for (int i = 0; i < 8; ++i) acc[i] = fmaxf(fmaf(acc[i], di, bias[i]), 0.f);
    } else {
      if (q == 0) sdinv[nl] = 0.f;
#pragma unroll
      for (int i = 0; i < 8; ++i) acc[i] = 0.f;
    }
    *(uint4*)&As[nl * LDA + q * 8] = pack8(acc);
  }
  __syncthreads();

  // phase 2: one wave per 16-col tile; 4 MFMAs each; h2s pre-scaled by dinv
  {
    const int wave = tid >> 6;
    const int lane = tid & 63;
    const int q = lane >> 4;
    const int l15 = lane & 15;
    f32x4 acc = {0.0f, 0.0f, 0.0f, 0.0f};
#pragma unroll
    for (int kk = 0; kk < 4; ++kk) {
      ABu a, b;
      a.u4 = *(const uint4*)&As[l15 * LDA + kk * 32 + q * 8];
      b.u4 = *(const uint4*)(Wb2 + ((size_t)(kk * 4 + q) * 64 + wave * 16 + l15) * 8);
      acc = __builtin_amdgcn_mfma_f32_16x16x32_bf16(a.v, b.v, acc, 0, 0, 0);
    }
#pragma unroll
    for (int v = 0; v < 4; ++v) {
      int rl = q * 4 + v;
      int row = blockIdx.x * 16 + rl;
      if (row < n) h2s[(size_t)row * 64 + wave * 16 + l15] = f2bf(acc[v] * sdinv[rl]);
    }
  }
}

// ---------------- 7: agg2 ----------------
// out[node,:] = di*(h2s[node] + sum h2s[esrc]) + b2 (h2s pre-scaled; fp32 out)
__global__ __launch_bounds__(256) void k_agg2(const unsigned short* __restrict__ h2s,
                                              const float* __restrict__ dinv,
                                              const float* __restrict__ b2,
                                              const int* __restrict__ offsets,
                                              const int* __restrict__ esrc,
                                              float* __restrict__ out, int n) {
  constexpr int CQ = 8;  // 64 ch / 8 per lane
  const int tid = threadIdx.x;
  const int node = blockIdx.x * 32 + tid / CQ;
  const int q = tid % CQ;
  if (node >= n) return;

  const uint4* h4 = (const uint4*)h2s;
  float di = dinv[node];
  float acc[8];
  unpack8(h4[(size_t)node * CQ + q], acc);

  int e0 = offsets[node];
  int e1 = offsets[node + 1];
  for (int e = e0; e < e1; e += 8) {
    int idx[8];
#pragma unroll
    for (int i = 0; i < 8; ++i) {
      int ee = e + i < e1 ? e + i : e1 - 1;
      idx[i] = esrc[ee];
    }
    uint4 rr[8];
#pragma unroll
    for (int i = 0; i < 8; ++i) rr[i] = h4[(size_t)idx[i] * CQ + q];
#pragma unroll
    for (int i = 0; i < 8; ++i) {
      float w = (e + i < e1) ? 1.f : 0.f;
      float g[8];
      unpack8(rr[i], g);
#pragma unroll
      for (int j = 0; j < 8; ++j) acc[j] = fmaf(g[j], w, acc[j]);
    }
  }

  const float4* b24 = (const float4*)b2;
  float4 ba = b24[q * 2], bb = b24[q * 2 + 1];
  float bias[8] = {ba.x, ba.y, ba.z, ba.w, bb.x, bb.y, bb.z, bb.w};
  float4 o0, o1;
  o0.x = fmaf(acc[0], di, bias[0]);
  o0.y = fmaf(acc[1], di, bias[1]);
  o0.z = fmaf(acc[2], di, bias[2]);
  o0.w = fmaf(acc[3], di, bias[3]);
  o1.x = fmaf(acc[4], di, bias[4]);
  o1.y = fmaf(acc[5], di, bias[5]);
  o1.z = fmaf(acc[6], di, bias[6]);
  o1.w = fmaf(acc[7], di, bias[7]);
  ((float4*)out)[(size_t)node * 16 + q * 2 + 0] = o0;
  ((float4*)out)[(size_t)node * 16 + q * 2 + 1] = o1;
}

// ---------------- launch ----------------

extern "C" void kernel_launch(void* const* d_in, const int* in_sizes, int n_in,
                              void* d_out, int out_size, void* d_ws, size_t ws_size,
                              hipStream_t stream) {
  const float* x  = (const float*)d_in[0];
  const float* W1 = (const float*)d_in[1];
  const float* b1 = (const float*)d_in[2];
  const float* W2 = (const float*)d_in[3];
  const float* b2 = (const float*)d_in[4];
  const int* src  = (const int*)d_in[5];
  const int* dst  = (const int*)d_in[6];
  float* out = (float*)d_out;

  constexpr int IN_C = 128, HID_C = 128, OUT_C = 64;
  const int N = in_sizes[0] / IN_C;   // 100000
  const int E = in_sizes[5];          // 600000

  char* p = (char*)d_ws;
  auto alloc = [&](size_t bytes) {
    char* r = p;
    p += (bytes + 255) & ~(size_t)255;
    return r;
  };
  float* dinv    = (float*)alloc((size_t)N * 4);
  int*   offsets = (int*)alloc((size_t)(N + 1) * 4);
  int*   counts  = (int*)alloc((size_t)N * 4);
  int*   cursor  = (int*)alloc((size_t)N * 4);
  int*   aux     = (int*)alloc(1024);
  int*   esrc    = (int*)alloc((size_t)E * 4);
  unsigned short* Wb1 = (unsigned short*)alloc((size_t)IN_C * HID_C * 2);
  unsigned short* Wb2 = (unsigned short*)alloc((size_t)HID_C * OUT_C * 2);
  unsigned short* h1s = (unsigned short*)alloc((size_t)N * HID_C * 2);
  unsigned short* h2s = (unsigned short*)alloc((size_t)N * OUT_C * 2);

  const int T = 256;
  const int G = (N + SCAN_CHUNK - 1) / SCAN_CHUNK;  // 98 (<= 256)
  const int EB = (E + T - 1) / T;                   // edge blocks (2344)
  const int GB = (N + 63) / 64;                     // gemm1 tiles (1563)
  constexpr int CONV_BLOCKS = (128 * 128 + 128 * 64) / 256;

  // split gemm1 tiles between dispatch 2 and dispatch 5, sized so each
  // interleaves 3:1 with the edge-parallel work
  const int EGRP = (EB + 2) / 3;          // 782 groups of 3 edge blocks
  const int GA = GB < EGRP ? GB : EGRP;   // gemm tiles in dispatch 2
  const int GBb = GB - GA;                // remaining tiles in dispatch 5
  const int ROW0 = GA * 64;

  k_pre<<<CONV_BLOCKS + (N + T - 1) / T, T, 0, stream>>>(W1, W2, Wb1, Wb2, counts, N);
  {
    int grp = EGRP > GA ? EGRP : GA;
    k_count_gemm1a<<<4 * grp, T, 0, stream>>>(dst, counts, E, x, Wb1, h1s, N, GA);
  }
  k_scan1<<<G, T, 0, stream>>>(counts, offsets, aux, N);
  k_scan3_dinv<<<(N + T - 1) / T, T, 0, stream>>>(offsets, aux, cursor, counts, dinv, N, E, G);
  {
    int grp = EGRP > GBb ? EGRP : GBb;
    k_fill_gemm1b<<<4 * grp, T, 0, stream>>>(src, dst, cursor, esrc, E, x, Wb1, h1s, N, ROW0);
  }
  k_aggemm<<<(N + 15) / 16, T, 0, stream>>>(h1s, dinv, b1, offsets, esrc, Wb2, h2s, N);
  k_agg2<<<(N + 31) / 32, T, 0, stream>>>(h2s, dinv, b2, offsets, esrc, out, N);
}

// Round 7
// 214.093 us; speedup vs baseline: 1.1490x; 1.1490x over previous
//
#include <hip/hip_runtime.h>
#include <math.h>

// GCN 2-layer: out = Anorm( relu( Anorm(X W1) + b1 ) W2 ) + b2
// R7: (a) rank-fusion — k_count's atomicAdd return value IS the edge's rank
//     in its dst bucket; store it (coalesced) and make the CSR fill an
//     atomic-free scatter esrc[offsets[dst]+rank] = src. Removes the 2nd
//     atomic pass (~40 us, was throughput-bound on returning atomics).
//     (b) de-unioned: R5/R6 showed atomic waves + MFMA waves don't overlap
//     usefully in one dispatch (64 us ~= sum, worse interleaved). Clean
//     dedicated dispatches; unions kept only for non-atomic convW+zero.

typedef __bf16 bf16x8 __attribute__((ext_vector_type(8)));
typedef float f32x4 __attribute__((ext_vector_type(4)));

union ABu {
  unsigned short u16[8];
  uint4 u4;
  bf16x8 v;
};

__device__ inline unsigned short f2bf(float f) {  // RNE
  unsigned u = __float_as_uint(f);
  return (unsigned short)((u + 0x7fffu + ((u >> 16) & 1u)) >> 16);
}

__device__ inline void unpack8(uint4 v, float* f) {
  f[0] = __uint_as_float(v.x << 16);
  f[1] = __uint_as_float(v.x & 0xffff0000u);
  f[2] = __uint_as_float(v.y << 16);
  f[3] = __uint_as_float(v.y & 0xffff0000u);
  f[4] = __uint_as_float(v.z << 16);
  f[5] = __uint_as_float(v.z & 0xffff0000u);
  f[6] = __uint_as_float(v.w << 16);
  f[7] = __uint_as_float(v.w & 0xffff0000u);
}

__device__ inline uint4 pack8(const float* a) {
  uint4 o;
  o.x = (unsigned)f2bf(a[0]) | ((unsigned)f2bf(a[1]) << 16);
  o.y = (unsigned)f2bf(a[2]) | ((unsigned)f2bf(a[3]) << 16);
  o.z = (unsigned)f2bf(a[4]) | ((unsigned)f2bf(a[5]) << 16);
  o.w = (unsigned)f2bf(a[6]) | ((unsigned)f2bf(a[7]) << 16);
  return o;
}

constexpr int SCAN_CHUNK = 1024;

// ---------------- 1: convW ∪ zero counts ----------------
// Wb[((k>>3)*N + n)*8 + (k&7)] = bf16(W[k*N+n])
__global__ __launch_bounds__(256) void k_pre(const float* __restrict__ W1,
                                             const float* __restrict__ W2,
                                             unsigned short* __restrict__ Wb1,
                                             unsigned short* __restrict__ Wb2,
                                             int* __restrict__ counts, int n) {
  constexpr int CONV_BLOCKS = (128 * 128 + 128 * 64) / 256;  // 96
  if (blockIdx.x < CONV_BLOCKS) {
    int idx = blockIdx.x * 256 + threadIdx.x;
    if (idx < 128 * 128) {
      int k = idx >> 7, c = idx & 127;
      Wb1[(((k >> 3) << 7) + c) * 8 + (k & 7)] = f2bf(W1[idx]);
    } else {
      int j = idx - 128 * 128;
      int k = j >> 6, c = j & 63;
      Wb2[(((k >> 3) << 6) + c) * 8 + (k & 7)] = f2bf(W2[j]);
    }
    return;
  }
  int i = (blockIdx.x - CONV_BLOCKS) * 256 + threadIdx.x;
  if (i < n) counts[i] = 0;
}

// ---------------- 2: gemm1 — h1s[M,128](bf16, UNSCALED) = X @ W1 ----------
// A-frag: A[m=lane&15][k=(lane>>4)*8+j]; C/D: col=lane&15, row=(lane>>4)*4+reg
__global__ __launch_bounds__(256) void k_gemm1(const float* __restrict__ X,
                                               const unsigned short* __restrict__ Wb,
                                               unsigned short* __restrict__ Cb, int M) {
  constexpr int K = 128, N = 128, NT = N / 16, KS = K / 32;
  const int tid = threadIdx.x;
  const int wave = tid >> 6;
  const int lane = tid & 63;
  const int q = lane >> 4;
  const int l15 = lane & 15;
  const int row0 = blockIdx.x * 64 + wave * 16;
  const int rowA = row0 + l15;

  f32x4 zero = {0.0f, 0.0f, 0.0f, 0.0f};
  f32x4 acc[NT];
#pragma unroll
  for (int t = 0; t < NT; ++t) acc[t] = zero;

#pragma unroll
  for (int kk = 0; kk < KS; ++kk) {
    ABu a;
    float4 f0 = make_float4(0.f, 0.f, 0.f, 0.f);
    float4 f1 = make_float4(0.f, 0.f, 0.f, 0.f);
    if (rowA < M) {
      const float4* ap = (const float4*)(X + (size_t)rowA * K + kk * 32 + q * 8);
      f0 = ap[0];
      f1 = ap[1];
    }
    a.u16[0] = f2bf(f0.x); a.u16[1] = f2bf(f0.y);
    a.u16[2] = f2bf(f0.z); a.u16[3] = f2bf(f0.w);
    a.u16[4] = f2bf(f1.x); a.u16[5] = f2bf(f1.y);
    a.u16[6] = f2bf(f1.z); a.u16[7] = f2bf(f1.w);
#pragma unroll
    for (int nt = 0; nt < NT; ++nt) {
      ABu b;
      b.u4 = *(const uint4*)(Wb + ((size_t)(kk * 4 + q) * N + nt * 16 + l15) * 8);
      acc[nt] = __builtin_amdgcn_mfma_f32_16x16x32_bf16(a.v, b.v, acc[nt], 0, 0, 0);
    }
  }

#pragma unroll
  for (int v = 0; v < 4; ++v) {
    int row = row0 + q * 4 + v;
    if (row < M) {
#pragma unroll
      for (int nt = 0; nt < NT; ++nt)
        Cb[(size_t)row * N + nt * 16 + l15] = f2bf(acc[nt][v]);
    }
  }
}

// ---------------- 3: count + rank (atomic return value reused) ----------
__global__ void k_count_rank(const int* __restrict__ dst, int* __restrict__ counts,
                             int* __restrict__ rank, int E) {
  int e = blockIdx.x * blockDim.x + threadIdx.x;
  if (e < E) rank[e] = atomicAdd(&counts[dst[e]], 1);
}

// ---------------- 4: per-chunk scan ----------------
__global__ __launch_bounds__(256) void k_scan1(const int* __restrict__ counts,
                                               int* __restrict__ offsets,
                                               int* __restrict__ aux, int n) {
  __shared__ int tsum[256];
  int tid = threadIdx.x;
  int base = blockIdx.x * SCAN_CHUNK + tid * 4;
  int v0 = (base + 0 < n) ? counts[base + 0] : 0;
  int v1 = (base + 1 < n) ? counts[base + 1] : 0;
  int v2 = (base + 2 < n) ? counts[base + 2] : 0;
  int v3 = (base + 3 < n) ? counts[base + 3] : 0;
  int s = v0 + v1 + v2 + v3;
  tsum[tid] = s;
  __syncthreads();
  for (int off = 1; off < 256; off <<= 1) {
    int t = (tid >= off) ? tsum[tid - off] : 0;
    __syncthreads();
    tsum[tid] += t;
    __syncthreads();
  }
  int excl = tsum[tid] - s;
  if (base + 0 < n) offsets[base + 0] = excl;
  if (base + 1 < n) offsets[base + 1] = excl + v0;
  if (base + 2 < n) offsets[base + 2] = excl + v0 + v1;
  if (base + 3 < n) offsets[base + 3] = excl + v0 + v1 + v2;
  if (tid == 255) aux[blockIdx.x] = tsum[255];
}

// ---------------- 5: aux-scan (redundant/block) + fixup + dinv ------------
__global__ __launch_bounds__(256) void k_scan3_dinv(int* __restrict__ offsets,
                                                    const int* __restrict__ aux,
                                                    const int* __restrict__ counts,
                                                    float* __restrict__ dinv,
                                                    int n, int E, int G) {
  __shared__ int saux[256];
  int tid = threadIdx.x;
  int v = (tid < G) ? aux[tid] : 0;
  saux[tid] = v;
  __syncthreads();
  for (int off = 1; off < 256; off <<= 1) {
    int t = (tid >= off) ? saux[tid - off] : 0;
    __syncthreads();
    saux[tid] += t;
    __syncthreads();
  }
  int excl = saux[tid] - v;
  __syncthreads();
  saux[tid] = excl;
  __syncthreads();

  int i = blockIdx.x * 256 + tid;
  if (i < n) {
    offsets[i] += saux[i >> 10];
    dinv[i] = rsqrtf((float)(counts[i] + 1));
  }
  if (i == 0) offsets[n] = E;
}

// ---------------- 6: atomic-free CSR scatter ----------------
__global__ void k_scatter(const int* __restrict__ src, const int* __restrict__ dst,
                          const int* __restrict__ offsets, const int* __restrict__ rank,
                          int* __restrict__ esrc, int E) {
  int e = blockIdx.x * blockDim.x + threadIdx.x;
  if (e < E) esrc[offsets[dst[e]] + rank[e]] = src[e];
}

// ---------------- 7: fused agg1 + GEMM2 ----------------
// acc = dinv[node]*h1[node] + sum_e dinv[esrc]*h1[esrc]
// ag = bf16(relu(dinv[node]*acc + b1)) -> LDS; h2s = (ag @ W2) * dinv (bf16)
__global__ __launch_bounds__(256) void k_aggemm(const unsigned short* __restrict__ h1s,
                                                const float* __restrict__ dinv,
                                                const float* __restrict__ b1,
                                                const int* __restrict__ offsets,
                                                const int* __restrict__ esrc,
                                                const unsigned short* __restrict__ Wb2,
                                                unsigned short* __restrict__ h2s,
                                                int n) {
  constexpr int LDA = 136;  // 128 + 8 pad, rows 16B-aligned
  __shared__ unsigned short As[16 * LDA];
  __shared__ float sdinv[16];
  const int tid = threadIdx.x;

  // phase 1: 16 nodes, 16 lanes each (8 ch/lane); masked unroll-8 gather
  {
    const int nl = tid >> 4;
    const int q = tid & 15;
    const int node = blockIdx.x * 16 + nl;
    float acc[8];
    if (node < n) {
      const uint4* h4 = (const uint4*)h1s;
      float di = dinv[node];
      if (q == 0) sdinv[nl] = di;
      float hs[8];
      unpack8(h4[(size_t)node * 16 + q], hs);
#pragma unroll
      for (int i = 0; i < 8; ++i) acc[i] = hs[i] * di;  // self (h1 unscaled)
      int e0 = offsets[node];
      int e1 = offsets[node + 1];
      for (int e = e0; e < e1; e += 8) {
        int idx[8];
#pragma unroll
        for (int i = 0; i < 8; ++i) {
          int ee = e + i < e1 ? e + i : e1 - 1;
          idx[i] = esrc[ee];
        }
        uint4 rr[8];
        float dv[8];
#pragma unroll
        for (int i = 0; i < 8; ++i) {
          rr[i] = h4[(size_t)idx[i] * 16 + q];
          dv[i] = dinv[idx[i]];
        }
#pragma unroll
        for (int i = 0; i < 8; ++i) {
          float w = (e + i < e1) ? dv[i] : 0.f;
          float g[8];
          unpack8(rr[i], g);
#pragma unroll
          for (int j = 0; j < 8; ++j) acc[j] = fmaf(g[j], w, acc[j]);
        }
      }
      const float4* b14 = (const float4*)b1;
      float4 ba = b14[q * 2], bb = b14[q * 2 + 1];
      float bias[8] = {ba.x, ba.y, ba.z, ba.w, bb.x, bb.y, bb.z, bb.w};
#pragma unroll
      for (int i = 0; i < 8; ++i) acc[i] = fmaxf(fmaf(acc[i], di, bias[i]), 0.f);
    } else {
      if (q == 0) sdinv[nl] = 0.f;
#pragma unroll
      for (int i = 0; i < 8; ++i) acc[i] = 0.f;
    }
    *(uint4*)&As[nl * LDA + q * 8] = pack8(acc);
  }
  __syncthreads();

  // phase 2: one wave per 16-col tile; 4 MFMAs each; h2s pre-scaled by dinv
  {
    const int wave = tid >> 6;
    const int lane = tid & 63;
    const int q = lane >> 4;
    const int l15 = lane & 15;
    f32x4 acc = {0.0f, 0.0f, 0.0f, 0.0f};
#pragma unroll
    for (int kk = 0; kk < 4; ++kk) {
      ABu a, b;
      a.u4 = *(const uint4*)&As[l15 * LDA + kk * 32 + q * 8];
      b.u4 = *(const uint4*)(Wb2 + ((size_t)(kk * 4 + q) * 64 + wave * 16 + l15) * 8);
      acc = __builtin_amdgcn_mfma_f32_16x16x32_bf16(a.v, b.v, acc, 0, 0, 0);
    }
#pragma unroll
    for (int v = 0; v < 4; ++v) {
      int rl = q * 4 + v;
      int row = blockIdx.x * 16 + rl;
      if (row < n) h2s[(size_t)row * 64 + wave * 16 + l15] = f2bf(acc[v] * sdinv[rl]);
    }
  }
}

// ---------------- 8: agg2 ----------------
// out[node,:] = di*(h2s[node] + sum h2s[esrc]) + b2 (h2s pre-scaled; fp32 out)
__global__ __launch_bounds__(256) void k_agg2(const unsigned short* __restrict__ h2s,
                                              const float* __restrict__ dinv,
                                              const float* __restrict__ b2,
                                              const int* __restrict__ offsets,
                                              const int* __restrict__ esrc,
                                              float* __restrict__ out, int n) {
  constexpr int CQ = 8;  // 64 ch / 8 per lane
  const int tid = threadIdx.x;
  const int node = blockIdx.x * 32 + tid / CQ;
  const int q = tid % CQ;
  if (node >= n) return;

  const uint4* h4 = (const uint4*)h2s;
  float di = dinv[node];
  float acc[8];
  unpack8(h4[(size_t)node * CQ + q], acc);

  int e0 = offsets[node];
  int e1 = offsets[node + 1];
  for (int e = e0; e < e1; e += 8) {
    int idx[8];
#pragma unroll
    for (int i = 0; i < 8; ++i) {
      int ee = e + i < e1 ? e + i : e1 - 1;
      idx[i] = esrc[ee];
    }
    uint4 rr[8];
#pragma unroll
    for (int i = 0; i < 8; ++i) rr[i] = h4[(size_t)idx[i] * CQ + q];
#pragma unroll
    for (int i = 0; i < 8; ++i) {
      float w = (e + i < e1) ? 1.f : 0.f;
      float g[8];
      unpack8(rr[i], g);
#pragma unroll
      for (int j = 0; j < 8; ++j) acc[j] = fmaf(g[j], w, acc[j]);
    }
  }

  const float4* b24 = (const float4*)b2;
  float4 ba = b24[q * 2], bb = b24[q * 2 + 1];
  float bias[8] = {ba.x, ba.y, ba.z, ba.w, bb.x, bb.y, bb.z, bb.w};
  float4 o0, o1;
  o0.x = fmaf(acc[0], di, bias[0]);
  o0.y = fmaf(acc[1], di, bias[1]);
  o0.z = fmaf(acc[2], di, bias[2]);
  o0.w = fmaf(acc[3], di, bias[3]);
  o1.x = fmaf(acc[4], di, bias[4]);
  o1.y = fmaf(acc[5], di, bias[5]);
  o1.z = fmaf(acc[6], di, bias[6]);
  o1.w = fmaf(acc[7], di, bias[7]);
  ((float4*)out)[(size_t)node * 16 + q * 2 + 0] = o0;
  ((float4*)out)[(size_t)node * 16 + q * 2 + 1] = o1;
}

// ---------------- launch ----------------

extern "C" void kernel_launch(void* const* d_in, const int* in_sizes, int n_in,
                              void* d_out, int out_size, void* d_ws, size_t ws_size,
                              hipStream_t stream) {
  const float* x  = (const float*)d_in[0];
  const float* W1 = (const float*)d_in[1];
  const float* b1 = (const float*)d_in[2];
  const float* W2 = (const float*)d_in[3];
  const float* b2 = (const float*)d_in[4];
  const int* src  = (const int*)d_in[5];
  const int* dst  = (const int*)d_in[6];
  float* out = (float*)d_out;

  constexpr int IN_C = 128, HID_C = 128, OUT_C = 64;
  const int N = in_sizes[0] / IN_C;   // 100000
  const int E = in_sizes[5];          // 600000

  char* p = (char*)d_ws;
  auto alloc = [&](size_t bytes) {
    char* r = p;
    p += (bytes + 255) & ~(size_t)255;
    return r;
  };
  float* dinv    = (float*)alloc((size_t)N * 4);
  int*   offsets = (int*)alloc((size_t)(N + 1) * 4);
  int*   counts  = (int*)alloc((size_t)N * 4);
  int*   rank    = (int*)alloc((size_t)E * 4);
  int*   aux     = (int*)alloc(1024);
  int*   esrc    = (int*)alloc((size_t)E * 4);
  unsigned short* Wb1 = (unsigned short*)alloc((size_t)IN_C * HID_C * 2);
  unsigned short* Wb2 = (unsigned short*)alloc((size_t)HID_C * OUT_C * 2);
  unsigned short* h1s = (unsigned short*)alloc((size_t)N * HID_C * 2);
  unsigned short* h2s = (unsigned short*)alloc((size_t)N * OUT_C * 2);

  const int T = 256;
  const int G = (N + SCAN_CHUNK - 1) / SCAN_CHUNK;  // 98 (<= 256)
  constexpr int CONV_BLOCKS = (128 * 128 + 128 * 64) / 256;

  k_pre<<<CONV_BLOCKS + (N + T - 1) / T, T, 0, stream>>>(W1, W2, Wb1, Wb2, counts, N);
  k_gemm1<<<(N + 63) / 64, T, 0, stream>>>(x, Wb1, h1s, N);
  k_count_rank<<<(E + T - 1) / T, T, 0, stream>>>(dst, counts, rank, E);
  k_scan1<<<G, T, 0, stream>>>(counts, offsets, aux, N);
  k_scan3_dinv<<<(N + T - 1) / T, T, 0, stream>>>(offsets, aux, counts, dinv, N, E, G);
  k_scatter<<<(E + T - 1) / T, T, 0, stream>>>(src, dst, offsets, rank, esrc, E);
  k_aggemm<<<(N + 15) / 16, T, 0, stream>>>(h1s, dinv, b1, offsets, esrc, Wb2, h2s, N);
  k_agg2<<<(N + 31) / 32, T, 0, stream>>>(h2s, dinv, b2, offsets, esrc, out, N);
}

// Round 8
// 211.173 us; speedup vs baseline: 1.1649x; 1.0138x over previous
//
#include <hip/hip_runtime.h>
#include <math.h>

// GCN 2-layer: out = Anorm( relu( Anorm(X W1) + b1 ) W2 ) + b2
// R8: (a) count_rank & scatter process 4 edges/thread (4 returning atomics
//     in flight per lane — the pass is outstanding-slot bound, not BW);
//     (b) dinv folded into scan1; gemm1 re-scaled (h1s = dinv[row]*X@W1) so
//     aggemm has NO per-edge dinv gather (stream is serial; R6 decoupling
//     bought nothing); (c) scan3 = offsets fixup only.

typedef __bf16 bf16x8 __attribute__((ext_vector_type(8)));
typedef float f32x4 __attribute__((ext_vector_type(4)));

union ABu {
  unsigned short u16[8];
  uint4 u4;
  bf16x8 v;
};

__device__ inline unsigned short f2bf(float f) {  // RNE
  unsigned u = __float_as_uint(f);
  return (unsigned short)((u + 0x7fffu + ((u >> 16) & 1u)) >> 16);
}

__device__ inline void unpack8(uint4 v, float* f) {
  f[0] = __uint_as_float(v.x << 16);
  f[1] = __uint_as_float(v.x & 0xffff0000u);
  f[2] = __uint_as_float(v.y << 16);
  f[3] = __uint_as_float(v.y & 0xffff0000u);
  f[4] = __uint_as_float(v.z << 16);
  f[5] = __uint_as_float(v.z & 0xffff0000u);
  f[6] = __uint_as_float(v.w << 16);
  f[7] = __uint_as_float(v.w & 0xffff0000u);
}

__device__ inline uint4 pack8(const float* a) {
  uint4 o;
  o.x = (unsigned)f2bf(a[0]) | ((unsigned)f2bf(a[1]) << 16);
  o.y = (unsigned)f2bf(a[2]) | ((unsigned)f2bf(a[3]) << 16);
  o.z = (unsigned)f2bf(a[4]) | ((unsigned)f2bf(a[5]) << 16);
  o.w = (unsigned)f2bf(a[6]) | ((unsigned)f2bf(a[7]) << 16);
  return o;
}

constexpr int SCAN_CHUNK = 1024;

// ---------------- 1: convW ∪ zero counts ----------------
__global__ __launch_bounds__(256) void k_pre(const float* __restrict__ W1,
                                             const float* __restrict__ W2,
                                             unsigned short* __restrict__ Wb1,
                                             unsigned short* __restrict__ Wb2,
                                             int* __restrict__ counts, int n) {
  constexpr int CONV_BLOCKS = (128 * 128 + 128 * 64) / 256;  // 96
  if (blockIdx.x < CONV_BLOCKS) {
    int idx = blockIdx.x * 256 + threadIdx.x;
    if (idx < 128 * 128) {
      int k = idx >> 7, c = idx & 127;
      Wb1[(((k >> 3) << 7) + c) * 8 + (k & 7)] = f2bf(W1[idx]);
    } else {
      int j = idx - 128 * 128;
      int k = j >> 6, c = j & 63;
      Wb2[(((k >> 3) << 6) + c) * 8 + (k & 7)] = f2bf(W2[j]);
    }
    return;
  }
  int i = (blockIdx.x - CONV_BLOCKS) * 256 + threadIdx.x;
  if (i < n) counts[i] = 0;
}

// ---------------- 2: count + rank, 4 edges/thread ----------------
__global__ __launch_bounds__(256) void k_count_rank(const int* __restrict__ dst,
                                                    int* __restrict__ counts,
                                                    int* __restrict__ rank, int E) {
  int base = (blockIdx.x * 256 + threadIdx.x) * 4;
  if (base + 3 < E) {
    int4 d = *(const int4*)(dst + base);
    int4 r;
    r.x = atomicAdd(&counts[d.x], 1);
    r.y = atomicAdd(&counts[d.y], 1);
    r.z = atomicAdd(&counts[d.z], 1);
    r.w = atomicAdd(&counts[d.w], 1);
    *(int4*)(rank + base) = r;
  } else {
    for (int e = base; e < E; ++e) rank[e] = atomicAdd(&counts[dst[e]], 1);
  }
}

// ---------------- 3: per-chunk scan + dinv ----------------
__global__ __launch_bounds__(256) void k_scan1(const int* __restrict__ counts,
                                               int* __restrict__ offsets,
                                               int* __restrict__ aux,
                                               float* __restrict__ dinv, int n) {
  __shared__ int tsum[256];
  int tid = threadIdx.x;
  int base = blockIdx.x * SCAN_CHUNK + tid * 4;
  int v0 = (base + 0 < n) ? counts[base + 0] : 0;
  int v1 = (base + 1 < n) ? counts[base + 1] : 0;
  int v2 = (base + 2 < n) ? counts[base + 2] : 0;
  int v3 = (base + 3 < n) ? counts[base + 3] : 0;
  int s = v0 + v1 + v2 + v3;
  tsum[tid] = s;
  __syncthreads();
  for (int off = 1; off < 256; off <<= 1) {
    int t = (tid >= off) ? tsum[tid - off] : 0;
    __syncthreads();
    tsum[tid] += t;
    __syncthreads();
  }
  int excl = tsum[tid] - s;
  if (base + 0 < n) { offsets[base + 0] = excl;              dinv[base + 0] = rsqrtf((float)(v0 + 1)); }
  if (base + 1 < n) { offsets[base + 1] = excl + v0;         dinv[base + 1] = rsqrtf((float)(v1 + 1)); }
  if (base + 2 < n) { offsets[base + 2] = excl + v0 + v1;    dinv[base + 2] = rsqrtf((float)(v2 + 1)); }
  if (base + 3 < n) { offsets[base + 3] = excl + v0 + v1 + v2; dinv[base + 3] = rsqrtf((float)(v3 + 1)); }
  if (tid == 255) aux[blockIdx.x] = tsum[255];
}

// ---------------- 4: aux-scan (redundant/block) + offsets fixup ------------
__global__ __launch_bounds__(256) void k_scan3(int* __restrict__ offsets,
                                               const int* __restrict__ aux,
                                               int n, int E, int G) {
  __shared__ int saux[256];
  int tid = threadIdx.x;
  int v = (tid < G) ? aux[tid] : 0;
  saux[tid] = v;
  __syncthreads();
  for (int off = 1; off < 256; off <<= 1) {
    int t = (tid >= off) ? saux[tid - off] : 0;
    __syncthreads();
    saux[tid] += t;
    __syncthreads();
  }
  int excl = saux[tid] - v;
  __syncthreads();
  saux[tid] = excl;
  __syncthreads();

  int i = blockIdx.x * 256 + tid;
  if (i < n) offsets[i] += saux[i >> 10];
  if (i == 0) offsets[n] = E;
}

// ---------------- 5: atomic-free CSR scatter, 4 edges/thread --------------
__global__ __launch_bounds__(256) void k_scatter(const int* __restrict__ src,
                                                 const int* __restrict__ dst,
                                                 const int* __restrict__ offsets,
                                                 const int* __restrict__ rank,
                                                 int* __restrict__ esrc, int E) {
  int base = (blockIdx.x * 256 + threadIdx.x) * 4;
  if (base + 3 < E) {
    int4 s = *(const int4*)(src + base);
    int4 d = *(const int4*)(dst + base);
    int4 r = *(const int4*)(rank + base);
    esrc[offsets[d.x] + r.x] = s.x;
    esrc[offsets[d.y] + r.y] = s.y;
    esrc[offsets[d.z] + r.z] = s.z;
    esrc[offsets[d.w] + r.w] = s.w;
  } else {
    for (int e = base; e < E; ++e) esrc[offsets[dst[e]] + rank[e]] = src[e];
  }
}

// ---------------- 6: gemm1 — h1s[M,128](bf16) = dinv[row] * (X @ W1) -------
// A-frag: A[m=lane&15][k=(lane>>4)*8+j]; C/D: col=lane&15, row=(lane>>4)*4+reg
__global__ __launch_bounds__(256) void k_gemm1(const float* __restrict__ X,
                                               const unsigned short* __restrict__ Wb,
                                               const float* __restrict__ dinv,
                                               unsigned short* __restrict__ Cb, int M) {
  constexpr int K = 128, N = 128, NT = N / 16, KS = K / 32;
  const int tid = threadIdx.x;
  const int wave = tid >> 6;
  const int lane = tid & 63;
  const int q = lane >> 4;
  const int l15 = lane & 15;
  const int row0 = blockIdx.x * 64 + wave * 16;
  const int rowA = row0 + l15;

  f32x4 zero = {0.0f, 0.0f, 0.0f, 0.0f};
  f32x4 acc[NT];
#pragma unroll
  for (int t = 0; t < NT; ++t) acc[t] = zero;

#pragma unroll
  for (int kk = 0; kk < KS; ++kk) {
    ABu a;
    float4 f0 = make_float4(0.f, 0.f, 0.f, 0.f);
    float4 f1 = make_float4(0.f, 0.f, 0.f, 0.f);
    if (rowA < M) {
      const float4* ap = (const float4*)(X + (size_t)rowA * K + kk * 32 + q * 8);
      f0 = ap[0];
      f1 = ap[1];
    }
    a.u16[0] = f2bf(f0.x); a.u16[1] = f2bf(f0.y);
    a.u16[2] = f2bf(f0.z); a.u16[3] = f2bf(f0.w);
    a.u16[4] = f2bf(f1.x); a.u16[5] = f2bf(f1.y);
    a.u16[6] = f2bf(f1.z); a.u16[7] = f2bf(f1.w);
#pragma unroll
    for (int nt = 0; nt < NT; ++nt) {
      ABu b;
      b.u4 = *(const uint4*)(Wb + ((size_t)(kk * 4 + q) * N + nt * 16 + l15) * 8);
      acc[nt] = __builtin_amdgcn_mfma_f32_16x16x32_bf16(a.v, b.v, acc[nt], 0, 0, 0);
    }
  }

#pragma unroll
  for (int v = 0; v < 4; ++v) {
    int row = row0 + q * 4 + v;
    if (row < M) {
      float di = dinv[row];
#pragma unroll
      for (int nt = 0; nt < NT; ++nt)
        Cb[(size_t)row * N + nt * 16 + l15] = f2bf(acc[nt][v] * di);
    }
  }
}

// ---------------- 7: fused agg1 + GEMM2 ----------------
// inner = h1s[node] + sum_e h1s[esrc]           (h1s pre-scaled by dinv)
// ag = bf16(relu(dinv[node]*inner + b1)) -> LDS; h2s = (ag @ W2) * dinv (bf16)
__global__ __launch_bounds__(256) void k_aggemm(const unsigned short* __restrict__ h1s,
                                                const float* __restrict__ dinv,
                                                const float* __restrict__ b1,
                                                const int* __restrict__ offsets,
                                                const int* __restrict__ esrc,
                                                const unsigned short* __restrict__ Wb2,
                                                unsigned short* __restrict__ h2s,
                                                int n) {
  constexpr int LDA = 136;  // 128 + 8 pad, rows 16B-aligned
  __shared__ unsigned short As[16 * LDA];
  __shared__ float sdinv[16];
  const int tid = threadIdx.x;

  // phase 1: 16 nodes, 16 lanes each (8 ch/lane); masked unroll-8 gather
  {
    const int nl = tid >> 4;
    const int q = tid & 15;
    const int node = blockIdx.x * 16 + nl;
    float acc[8];
    if (node < n) {
      const uint4* h4 = (const uint4*)h1s;
      float di = dinv[node];
      if (q == 0) sdinv[nl] = di;
      unpack8(h4[(size_t)node * 16 + q], acc);  // self (pre-scaled)
      int e0 = offsets[node];
      int e1 = offsets[node + 1];
      for (int e = e0; e < e1; e += 8) {
        int idx[8];
#pragma unroll
        for (int i = 0; i < 8; ++i) {
          int ee = e + i < e1 ? e + i : e1 - 1;
          idx[i] = esrc[ee];
        }
        uint4 rr[8];
#pragma unroll
        for (int i = 0; i < 8; ++i) rr[i] = h4[(size_t)idx[i] * 16 + q];
#pragma unroll
        for (int i = 0; i < 8; ++i) {
          float w = (e + i < e1) ? 1.f : 0.f;
          float g[8];
          unpack8(rr[i], g);
#pragma unroll
          for (int j = 0; j < 8; ++j) acc[j] = fmaf(g[j], w, acc[j]);
        }
      }
      const float4* b14 = (const float4*)b1;
      float4 ba = b14[q * 2], bb = b14[q * 2 + 1];
      float bias[8] = {ba.x, ba.y, ba.z, ba.w, bb.x, bb.y, bb.z, bb.w};
#pragma unroll
      for (int i = 0; i < 8; ++i) acc[i] = fmaxf(fmaf(acc[i], di, bias[i]), 0.f);
    } else {
      if (q == 0) sdinv[nl] = 0.f;
#pragma unroll
      for (int i = 0; i < 8; ++i) acc[i] = 0.f;
    }
    *(uint4*)&As[nl * LDA + q * 8] = pack8(acc);
  }
  __syncthreads();

  // phase 2: one wave per 16-col tile; 4 MFMAs each; h2s pre-scaled by dinv
  {
    const int wave = tid >> 6;
    const int lane = tid & 63;
    const int q = lane >> 4;
    const int l15 = lane & 15;
    f32x4 acc = {0.0f, 0.0f, 0.0f, 0.0f};
#pragma unroll
    for (int kk = 0; kk < 4; ++kk) {
      ABu a, b;
      a.u4 = *(const uint4*)&As[l15 * LDA + kk * 32 + q * 8];
      b.u4 = *(const uint4*)(Wb2 + ((size_t)(kk * 4 + q) * 64 + wave * 16 + l15) * 8);
      acc = __builtin_amdgcn_mfma_f32_16x16x32_bf16(a.v, b.v, acc, 0, 0, 0);
    }
#pragma unroll
    for (int v = 0; v < 4; ++v) {
      int rl = q * 4 + v;
      int row = blockIdx.x * 16 + rl;
      if (row < n) h2s[(size_t)row * 64 + wave * 16 + l15] = f2bf(acc[v] * sdinv[rl]);
    }
  }
}

// ---------------- 8: agg2 ----------------
// out[node,:] = di*(h2s[node] + sum h2s[esrc]) + b2 (h2s pre-scaled; fp32 out)
__global__ __launch_bounds__(256) void k_agg2(const unsigned short* __restrict__ h2s,
                                              const float* __restrict__ dinv,
                                              const float* __restrict__ b2,
                                              const int* __restrict__ offsets,
                                              const int* __restrict__ esrc,
                                              float* __restrict__ out, int n) {
  constexpr int CQ = 8;  // 64 ch / 8 per lane
  const int tid = threadIdx.x;
  const int node = blockIdx.x * 32 + tid / CQ;
  const int q = tid % CQ;
  if (node >= n) return;

  const uint4* h4 = (const uint4*)h2s;
  float di = dinv[node];
  float acc[8];
  unpack8(h4[(size_t)node * CQ + q], acc);

  int e0 = offsets[node];
  int e1 = offsets[node + 1];
  for (int e = e0; e < e1; e += 8) {
    int idx[8];
#pragma unroll
    for (int i = 0; i < 8; ++i) {
      int ee = e + i < e1 ? e + i : e1 - 1;
      idx[i] = esrc[ee];
    }
    uint4 rr[8];
#pragma unroll
    for (int i = 0; i < 8; ++i) rr[i] = h4[(size_t)idx[i] * CQ + q];
#pragma unroll
    for (int i = 0; i < 8; ++i) {
      float w = (e + i < e1) ? 1.f : 0.f;
      float g[8];
      unpack8(rr[i], g);
#pragma unroll
      for (int j = 0; j < 8; ++j) acc[j] = fmaf(g[j], w, acc[j]);
    }
  }

  const float4* b24 = (const float4*)b2;
  float4 ba = b24[q * 2], bb = b24[q * 2 + 1];
  float bias[8] = {ba.x, ba.y, ba.z, ba.w, bb.x, bb.y, bb.z, bb.w};
  float4 o0, o1;
  o0.x = fmaf(acc[0], di, bias[0]);
  o0.y = fmaf(acc[1], di, bias[1]);
  o0.z = fmaf(acc[2], di, bias[2]);
  o0.w = fmaf(acc[3], di, bias[3]);
  o1.x = fmaf(acc[4], di, bias[4]);
  o1.y = fmaf(acc[5], di, bias[5]);
  o1.z = fmaf(acc[6], di, bias[6]);
  o1.w = fmaf(acc[7], di, bias[7]);
  ((float4*)out)[(size_t)node * 16 + q * 2 + 0] = o0;
  ((float4*)out)[(size_t)node * 16 + q * 2 + 1] = o1;
}

// ---------------- launch ----------------

extern "C" void kernel_launch(void* const* d_in, const int* in_sizes, int n_in,
                              void* d_out, int out_size, void* d_ws, size_t ws_size,
                              hipStream_t stream) {
  const float* x  = (const float*)d_in[0];
  const float* W1 = (const float*)d_in[1];
  const float* b1 = (const float*)d_in[2];
  const float* W2 = (const float*)d_in[3];
  const float* b2 = (const float*)d_in[4];
  const int* src  = (const int*)d_in[5];
  const int* dst  = (const int*)d_in[6];
  float* out = (float*)d_out;

  constexpr int IN_C = 128, HID_C = 128, OUT_C = 64;
  const int N = in_sizes[0] / IN_C;   // 100000
  const int E = in_sizes[5];          // 600000

  char* p = (char*)d_ws;
  auto alloc = [&](size_t bytes) {
    char* r = p;
    p += (bytes + 255) & ~(size_t)255;
    return r;
  };
  float* dinv    = (float*)alloc((size_t)N * 4);
  int*   offsets = (int*)alloc((size_t)(N + 1) * 4);
  int*   counts  = (int*)alloc((size_t)N * 4);
  int*   rank    = (int*)alloc((size_t)E * 4);
  int*   aux     = (int*)alloc(1024);
  int*   esrc    = (int*)alloc((size_t)E * 4);
  unsigned short* Wb1 = (unsigned short*)alloc((size_t)IN_C * HID_C * 2);
  unsigned short* Wb2 = (unsigned short*)alloc((size_t)HID_C * OUT_C * 2);
  unsigned short* h1s = (unsigned short*)alloc((size_t)N * HID_C * 2);
  unsigned short* h2s = (unsigned short*)alloc((size_t)N * OUT_C * 2);

  const int T = 256;
  const int G = (N + SCAN_CHUNK - 1) / SCAN_CHUNK;  // 98 (<= 256)
  const int E4B = ((E + 3) / 4 + T - 1) / T;        // 4-edge/thread blocks
  constexpr int CONV_BLOCKS = (128 * 128 + 128 * 64) / 256;

  k_pre<<<CONV_BLOCKS + (N + T - 1) / T, T, 0, stream>>>(W1, W2, Wb1, Wb2, counts, N);
  k_count_rank<<<E4B, T, 0, stream>>>(dst, counts, rank, E);
  k_scan1<<<G, T, 0, stream>>>(counts, offsets, aux, dinv, N);
  k_scan3<<<(N + T - 1) / T, T, 0, stream>>>(offsets, aux, N, E, G);
  k_scatter<<<E4B, T, 0, stream>>>(src, dst, offsets, rank, esrc, E);
  k_gemm1<<<(N + 63) / 64, T, 0, stream>>>(x, Wb1, dinv, h1s, N);
  k_aggemm<<<(N + 15) / 16, T, 0, stream>>>(h1s, dinv, b1, offsets, esrc, Wb2, h2s, N);
  k_agg2<<<(N + 31) / 32, T, 0, stream>>>(h2s, dinv, b2, offsets, esrc, out, N);
}